// Round 8
// baseline (276.765 us; speedup 1.0000x reference)
//
#include <hip/hip_runtime.h>
#include <hip/hip_bf16.h>
#include <cstdint>
#include <cstddef>

// ============================================================================
// CA3RecurrentMatrix: retrieved = query @ pinv8(A) @ A
//
// Math: with M = A^T A (C x C), retrieved = query @ h8(M),
//   h8(x) = 1 - (1 - a*x)^256 = 256*a*x - O((a*x)^2), a*x <= ~7e-7.
// ||A||_F^2 = trace(M), computed in reduce4 from the bf16 partial sums.
//
// Pipeline (4 dispatches):
//   1. prep   : At = A^T bf16 + qb = bf16(query) + wsf[4]=0
//   2. gemm_m3: P[z] = bf16(At @ At^T over K-chunk z), split-K=4, 256^2 tile,
//               512 thr, 4-phase schedule (the round-1 gemm8<3> structure --
//               budget-inferred <78 us; the 128^2 rewrites of rounds 3-6 ran
//               ~130-145 us hidden below the top-5 cutoff and are reverted).
//               Partials in OUT buffer (bf16, 4 x 8 MiB of the 64 MiB out).
//               XCD-chunked: each XCD's block set touches exactly one 4 MiB
//               At z-slice = its L2.
//   3. reduce4: Mb = bf16(sum_z P[z]) + trace -> wsf[4]  (bf16 streams, 40MB)
//   4. gemm_qm: out = c1 * (qb @ Mb^T), 256^2 tile, single-barrier 4-phase
//               (round-6 variant, measured 82 us / 0 conflicts / FETCH 49 MB;
//               schedule pinned across 6 variants -- frozen).
//
// 4-phase K-tile schedule (both gemms; phase q = C-quadrant q, 16 MFMA):
//   q0: rd A-quad0 + B all (regs for whole tile); stA(t+1,h0)
//   q1: rd A-quad1;                               stA(t+1,h1)
//   q2: rd A-quad2;                               stB(t+2,h0)
//   q3: rd A-quad3; stB(t+2,h1); vmcnt(4)
// (gemm_m3: barrier/lgkm0 around MFMA per phase -- round-1 form.
//  gemm_qm: single-barrier form -- round-6 ledger in kernel comment.)
// Shared invariants:
//  - vmcnt(4)@q3 drains A(t+1), keeps B(t+2)'s 4 loads in flight; tail 0.
//  - stB@q2 overwrites Bs[buf] only after breg reg-capture drained @q0.
//  - stA@q0 overwrites As[buf^1], last read drained in t-1's final phase.
//  - LDS swizzle both-sides: physical 16B slot p of row r holds logical
//    k-slot p^(r&7); staging pre-swizzles the GLOBAL source column (linear
//    LDS dest, as global_load_lds requires), reads apply the same XOR.
// ============================================================================

#define K_DIM 4096
#define C_DIM 2048
#define B_DIM 8192
#define SPLITK 4
#define KCHUNK (K_DIM / SPLITK)

typedef __bf16 bf16x8 __attribute__((ext_vector_type(8)));
typedef float f32x4 __attribute__((ext_vector_type(4)));

#define VMCNT(n) asm volatile("s_waitcnt vmcnt(" #n ")" ::: "memory")
#define LGKMCNT0 asm volatile("s_waitcnt lgkmcnt(0)" ::: "memory")
#define SBAR __builtin_amdgcn_s_barrier()

__device__ __forceinline__ void async_load16(const void* g, void* l) {
  __builtin_amdgcn_global_load_lds(
      (const __attribute__((address_space(1))) void*)g,
      (__attribute__((address_space(3))) void*)l, 16, 0, 0);
}

// --------------------------- prep: transpose + cvt + wsf zero -------------
__global__ __launch_bounds__(256) void prep_kernel(
    const float* __restrict__ A, __hip_bfloat16* __restrict__ At,
    const float* __restrict__ q, __hip_bfloat16* __restrict__ qb,
    float* __restrict__ wsf) {
  const int b = blockIdx.x;
  const int t = threadIdx.x;
  if (b < 2048) {  // ---- transpose tile: A (K,C) fp32 -> At (C,K) bf16
    __shared__ __align__(16) __hip_bfloat16 Ts[64 * 68];
    const int c0 = (b & 31) * 64;
    const int k0 = (b >> 5) * 64;
    const int c_l = t & 63;
    const int kq = t >> 6;
#pragma unroll
    for (int i = 0; i < 4; ++i) {
      int k_l = i * 16 + kq * 4;
      union { __hip_bfloat16 h[4]; uint2 u; } pk;
#pragma unroll
      for (int j = 0; j < 4; ++j)
        pk.h[j] = __float2bfloat16(A[(size_t)(k0 + k_l + j) * C_DIM + c0 + c_l]);
      *(uint2*)(Ts + c_l * 68 + k_l) = pk.u;
    }
    __syncthreads();
    const int c = t >> 2;
    const int seg = t & 3;
    const __hip_bfloat16* src = Ts + c * 68 + seg * 16;
    union { uint2 d[2]; uint4 qv; } o0, o1;
    o0.d[0] = *(const uint2*)(src + 0);
    o0.d[1] = *(const uint2*)(src + 4);
    o1.d[0] = *(const uint2*)(src + 8);
    o1.d[1] = *(const uint2*)(src + 12);
    __hip_bfloat16* dst = At + (size_t)(c0 + c) * K_DIM + k0 + seg * 16;
    *(uint4*)(dst + 0) = o0.qv;
    *(uint4*)(dst + 8) = o1.qv;
  } else {  // ---- cvt query -> qb (1024 blocks, grid-stride)
    if (b == 2048 && t == 0) wsf[4] = 0.0f;
    const int n4 = B_DIM * C_DIM / 4;
    int tid = (b - 2048) * 256 + t;
    for (int i = tid; i < n4; i += 1024 * 256) {
      float4 v = ((const float4*)q)[i];
      __hip_bfloat16 o[4] = {__float2bfloat16(v.x), __float2bfloat16(v.y),
                             __float2bfloat16(v.z), __float2bfloat16(v.w)};
      *(uint2*)(qb + 4 * (size_t)i) = *(const uint2*)o;
    }
  }
}

// --------------------- gemm_m3: P[z] = bf16(At @ At^T), K-chunk z ---------
// Round-1 gemm8<3> structure: 256x256 tile, 8 waves (2Mx4N), wave tile
// 128x64, BK=64, double-buffered 128 KiB LDS, 4-phase 2-barrier schedule.
// Grid 256 = 8x8 tiles x 4 z, XCD-chunked: sw=(bid&7)*32+(bid>>3) is
// bijective; XCD i owns one half z-slice (4 tm x 8 tn) -> union At fetch
// per XCD = the whole 4 MiB z-slice = one XCD L2.
__global__ __launch_bounds__(512, 2) void gemm_m3(
    const __hip_bfloat16* __restrict__ At, __hip_bfloat16* __restrict__ P) {
  constexpr int BK = 64;
  constexpr int NT = KCHUNK / BK;  // 16
  __shared__ __align__(16) __hip_bfloat16 As[2][256 * BK];
  __shared__ __align__(16) __hip_bfloat16 Bs[2][256 * BK];
  const int bid = blockIdx.x;
  const int sw = (bid & 7) * 32 + (bid >> 3);
  const int z = sw >> 6;           // [0,4)
  const int rem = sw & 63;
  const int tm_i = rem >> 3;       // [0,8)
  const int tn_i = rem & 7;        // [0,8)
  const int tid = threadIdx.x;
  const int wave = tid >> 6, lane = tid & 63;
  const int tile_m = tm_i * 256, tile_n = tn_i * 256;
  const int kstart = z * KCHUNK;
  const int wm = (wave >> 2) * 128, wn = (wave & 3) * 64;
  const int lr = lane >> 3, lcl = (lane & 7) ^ lr;
  const __hip_bfloat16* aBase =
      At + (size_t)(tile_m + wave * 16 + lr) * K_DIM + kstart + lcl * 8;
  const __hip_bfloat16* bBase =
      At + (size_t)(tile_n + wave * 16 + lr) * K_DIM + kstart + lcl * 8;
  const int l15 = lane & 15, lg = lane >> 4, l7 = lane & 7;

  auto stA = [&](int buf, int h, int t) {
    const __hip_bfloat16* s = aBase + (size_t)(h * 128) * K_DIM + (size_t)t * BK;
    __hip_bfloat16* d = &As[buf][(h * 128 + wave * 16) * BK];
    async_load16(s, d);
    async_load16(s + (size_t)8 * K_DIM, d + 8 * BK);
  };
  auto stB = [&](int buf, int h, int t) {
    const __hip_bfloat16* s = bBase + (size_t)(h * 128) * K_DIM + (size_t)t * BK;
    __hip_bfloat16* d = &Bs[buf][(h * 128 + wave * 16) * BK];
    async_load16(s, d);
    async_load16(s + (size_t)8 * K_DIM, d + 8 * BK);
  };

  f32x4 acc[8][4] = {};

  // prologue: A(0), B(0) must land; B(1)'s 4 loads stay in flight
  stA(0, 0, 0); stA(0, 1, 0);
  stB(0, 0, 0); stB(0, 1, 0);
  stB(1, 0, 1); stB(1, 1, 1);
  VMCNT(4);
  SBAR;

  for (int t = 0; t < NT; ++t) {
    const int buf = t & 1;
    bf16x8 breg[4][2];
#pragma unroll
    for (int q = 0; q < 4; ++q) {
      bf16x8 af[2][2];
#pragma unroll
      for (int f = 0; f < 2; ++f)
#pragma unroll
        for (int s = 0; s < 2; ++s)
          af[f][s] = *(const bf16x8*)&As[buf][(wm + q * 32 + f * 16 + l15) * BK +
                                             ((((s << 2) | lg) ^ l7) << 3)];
      if (q == 0) {
#pragma unroll
        for (int j = 0; j < 4; ++j)
#pragma unroll
          for (int s = 0; s < 2; ++s)
            breg[j][s] = *(const bf16x8*)&Bs[buf][(wn + j * 16 + l15) * BK +
                                                 ((((s << 2) | lg) ^ l7) << 3)];
      }
      if (q == 0 && t + 1 < NT) stA(buf ^ 1, 0, t + 1);
      if (q == 1 && t + 1 < NT) stA(buf ^ 1, 1, t + 1);
      if (q == 2 && t + 2 < NT) stB(buf, 0, t + 2);
      if (q == 3) {
        if (t + 2 < NT) {
          stB(buf, 1, t + 2);
          VMCNT(4);
        } else {
          VMCNT(0);
        }
      }
      SBAR;
      LGKMCNT0;
      __builtin_amdgcn_s_setprio(1);
#pragma unroll
      for (int s = 0; s < 2; ++s)
#pragma unroll
        for (int f = 0; f < 2; ++f)
#pragma unroll
          for (int j = 0; j < 4; ++j)
            acc[q * 2 + f][j] = __builtin_amdgcn_mfma_f32_16x16x32_bf16(
                af[f][s], breg[j][s], acc[q * 2 + f][j], 0, 0, 0);
      __builtin_amdgcn_s_setprio(0);
      SBAR;
    }
  }

  // epilogue: bf16 partial. C/D (16x16): col = lane&15, row = (lane>>4)*4+reg
  __hip_bfloat16* Pz = P + (size_t)z * C_DIM * C_DIM;
#pragma unroll
  for (int m = 0; m < 8; ++m) {
    const int gm = tile_m + wm + m * 16 + lg * 4;
#pragma unroll
    for (int j = 0; j < 4; ++j) {
      const int gn = tile_n + wn + j * 16 + l15;
#pragma unroll
      for (int r = 0; r < 4; ++r)
        Pz[(size_t)(gm + r) * C_DIM + gn] = __float2bfloat16(acc[m][j][r]);
    }
  }
}

// ------------------- reduce4: Mb = bf16(sum P[z]) + trace -----------------
// bf16 partial streams (4 x 8 MiB read + 8 MiB write).
__global__ __launch_bounds__(256) void reduce4_kernel(
    const __hip_bfloat16* __restrict__ P, __hip_bfloat16* __restrict__ Mb,
    float* __restrict__ wsf) {
  const size_t CC = (size_t)C_DIM * C_DIM;
  const int n8 = (int)(CC / 8);
  int tid = blockIdx.x * blockDim.x + threadIdx.x;
  int stride = gridDim.x * blockDim.x;
  float tsum = 0.0f;
  bool hit = false;
  for (int i = tid; i < n8; i += stride) {
    float acc[8] = {};
#pragma unroll
    for (int z = 0; z < SPLITK; ++z) {
      uint4 raw = *(const uint4*)(P + z * CC + (size_t)i * 8);
      const __hip_bfloat16* h = (const __hip_bfloat16*)&raw;
#pragma unroll
      for (int j = 0; j < 8; ++j) acc[j] += __bfloat162float(h[j]);
    }
    __hip_bfloat16 o[8];
#pragma unroll
    for (int j = 0; j < 8; ++j) o[j] = __float2bfloat16(acc[j]);
    *(uint4*)(Mb + (size_t)i * 8) = *(const uint4*)o;
    // diag of row g sits at flat index g*(C_DIM+1); the 8-elem window
    // [8i, 8i+8) contains at most one (spacing 2049 > 8).
    const int e0 = 8 * i;
    const int g = e0 >> 11;
    const int d = g * (C_DIM + 1);
    if (d >= e0 && d < e0 + 8) {
      tsum += acc[d - e0];
      hit = true;
    }
  }
  if (hit) atomicAdd(wsf + 4, tsum);
}

// --------------------------- gemm_qm: out = c1 * qb @ Mb^T ----------------
// Single-barrier 4-phase schedule (round 6: 82 us, MfmaUtil 32, conflicts 0,
// FETCH 49 MB -- frozen). 256x256 tile, 8 waves (2Mx4N), wave tile 128x64,
// BK=64, double-buffered 128 KiB LDS. Grid 256, XCD-chunked.
// Ledger: stA@p0-post overwrites As[buf^1] (last reads drained lgkm0@
// p3-post(t-1), ordered by bar(p0,t)); stB@p3-post overwrites Bs[buf]
// (bfr reads drained lgkm0@p0/p2-post, ordered by bar(p3,t)); vmcnt(0)@
// region(p3) drains A(t+1)/B(t+1) (issued >=2 phases earlier, cheap);
// stB(t+2) issued after the vmcnt stays in flight 4 phases.
__global__ __launch_bounds__(512, 2) void gemm_qm(
    const __hip_bfloat16* __restrict__ Ab, const __hip_bfloat16* __restrict__ Bb,
    float* __restrict__ Fp, const float* __restrict__ ls,
    const float* __restrict__ wsf) {
  constexpr int BK = 64;
  constexpr int NT = C_DIM / BK;  // 32
  __shared__ __align__(16) __hip_bfloat16 As[2][256 * BK];
  __shared__ __align__(16) __hip_bfloat16 Bs[2][256 * BK];
  const int bid = blockIdx.x;
  const int sw = (bid & 7) * 32 + (bid >> 3);
  const int tn_i = sw & 7;    // [0,8)
  const int tm_i = sw >> 3;   // [0,32)
  const int tid = threadIdx.x;
  const int wave = tid >> 6, lane = tid & 63;
  const int tile_m = tm_i * 256, tile_n = tn_i * 256;
  const int wm = (wave >> 2) * 128, wn = (wave & 3) * 64;
  const int lr = lane >> 3, lcl = (lane & 7) ^ lr;
  const __hip_bfloat16* aBase =
      Ab + (size_t)(tile_m + wave * 16 + lr) * C_DIM + lcl * 8;
  const __hip_bfloat16* bBase =
      Bb + (size_t)(tile_n + wave * 16 + lr) * C_DIM + lcl * 8;
  const int l15 = lane & 15, lg = lane >> 4, l7 = lane & 7;

  auto stA = [&](int buf, int h, int t) {
    const __hip_bfloat16* s = aBase + (size_t)(h * 128) * C_DIM + (size_t)t * BK;
    __hip_bfloat16* d = &As[buf][(h * 128 + wave * 16) * BK];
    async_load16(s, d);
    async_load16(s + (size_t)8 * C_DIM, d + 8 * BK);
  };
  auto stB = [&](int buf, int h, int t) {
    const __hip_bfloat16* s = bBase + (size_t)(h * 128) * C_DIM + (size_t)t * BK;
    __hip_bfloat16* d = &Bs[buf][(h * 128 + wave * 16) * BK];
    async_load16(s, d);
    async_load16(s + (size_t)8 * C_DIM, d + 8 * BK);
  };

  f32x4 acc[8][4] = {};
  bf16x8 af[4], bfr[4];

  auto rdA = [&](int buf, int mh, int s) {
#pragma unroll
    for (int f = 0; f < 4; ++f)
      af[f] = *(const bf16x8*)&As[buf][(wm + mh * 64 + f * 16 + l15) * BK +
                                       (((s * 4 + lg) ^ l7) * 8)];
  };
  auto rdB = [&](int buf, int s) {
#pragma unroll
    for (int j = 0; j < 4; ++j)
      bfr[j] = *(const bf16x8*)&Bs[buf][(wn + j * 16 + l15) * BK +
                                        (((s * 4 + lg) ^ l7) * 8)];
  };
  auto mm = [&](int mh) {
    __builtin_amdgcn_s_setprio(1);
#pragma unroll
    for (int f = 0; f < 4; ++f)
#pragma unroll
      for (int j = 0; j < 4; ++j)
        acc[mh * 4 + f][j] = __builtin_amdgcn_mfma_f32_16x16x32_bf16(
            af[f], bfr[j], acc[mh * 4 + f][j], 0, 0, 0);
    __builtin_amdgcn_s_setprio(0);
  };

  // prologue: A(0),B(0) drained; B(1)'s 4 loads stay in flight
  stA(0, 0, 0); stA(0, 1, 0);
  stB(0, 0, 0); stB(0, 1, 0);
  stB(1, 0, 1); stB(1, 1, 1);
  VMCNT(4);
  SBAR;

  for (int t = 0; t < NT; ++t) {
    const int buf = t & 1;
    // ---- p0: (s0, mh0)
    rdA(buf, 0, 0);
    rdB(buf, 0);
    SBAR;
    if (t + 1 < NT) stA(buf ^ 1, 0, t + 1);
    LGKMCNT0;
    mm(0);
    // ---- p1: (s0, mh1)
    rdA(buf, 1, 0);
    SBAR;
    if (t + 1 < NT) stA(buf ^ 1, 1, t + 1);
    LGKMCNT0;
    mm(1);
    // ---- p2: (s1, mh0)
    rdA(buf, 0, 1);
    rdB(buf, 1);
    SBAR;
    LGKMCNT0;
    mm(0);
    // ---- p3: (s1, mh1)
    rdA(buf, 1, 1);
    VMCNT(0);  // drains A(t+1),B(t+1) (issued >=2 phases ago); cheap
    SBAR;
    if (t + 2 < NT) { stB(buf, 0, t + 2); stB(buf, 1, t + 2); }
    LGKMCNT0;
    mm(1);
  }

  // epilogue: C/D (16x16): col = lane&15, row = (lane>>4)*4 + reg
  const float c1 = 256.0f * fminf(expf(ls[0]), 5e-4f) / (wsf[4] + 1e-8f);
#pragma unroll
  for (int m = 0; m < 8; ++m) {
    const int gm = tile_m + wm + m * 16 + lg * 4;
#pragma unroll
    for (int j = 0; j < 4; ++j) {
      const int gn = tile_n + wn + j * 16 + l15;
#pragma unroll
      for (int r = 0; r < 4; ++r)
        Fp[(size_t)(gm + r) * C_DIM + gn] = c1 * acc[m][j][r];
    }
  }
}

// ------------------------------------------------------------- launch -----
extern "C" void kernel_launch(void* const* d_in, const int* in_sizes, int n_in,
                              void* d_out, int out_size, void* d_ws, size_t ws_size,
                              hipStream_t stream) {
  const float* query = (const float*)d_in[0];
  const float* A = (const float*)d_in[1];
  const float* ls = (const float*)d_in[2];
  float* out = (float*)d_out;

  char* ws = (char*)d_ws;
  float* wsf = (float*)ws;
  size_t off = 256;
  __hip_bfloat16* At = (__hip_bfloat16*)(ws + off);
  off += (size_t)C_DIM * K_DIM * 2;  // 16 MiB
  __hip_bfloat16* qb = (__hip_bfloat16*)(ws + off);
  off += (size_t)B_DIM * C_DIM * 2;  // 32 MiB
  __hip_bfloat16* Mb = (__hip_bfloat16*)(ws + off);  // 8 MiB

  // split-K bf16 partials live in the OUT buffer (4 x 8 MiB = 32 MiB of the
  // 64 MiB out); gemm_qm overwrites out afterwards (stream-ordered).
  __hip_bfloat16* P = (__hip_bfloat16*)out;

  // 1) At = A^T bf16 ; qb = bf16(query) ; wsf[4] = 0
  prep_kernel<<<3072, 256, 0, stream>>>(A, At, query, qb, wsf);
  // 2) P[z] = bf16(At @ At^T) over K-chunk z  (256 blocks, XCD-chunked)
  gemm_m3<<<256, 512, 0, stream>>>(At, P);
  // 3) Mb = bf16(sum_z P[z]) + trace -> wsf[4]
  reduce4_kernel<<<1024, 256, 0, stream>>>(P, Mb, wsf);
  // 4) out = c1 * qb @ Mb^T  (256 blocks, XCD-chunked)
  gemm_qm<<<256, 512, 0, stream>>>(qb, Mb, out, ls, wsf);
}

// Round 12
// 276.374 us; speedup vs baseline: 1.0014x; 1.0014x over previous
//
#include <hip/hip_runtime.h>
#include <hip/hip_bf16.h>
#include <cstdint>
#include <cstddef>

// ============================================================================
// CA3RecurrentMatrix: retrieved = query @ pinv8(A) @ A
//
// Math: with M = A^T A (C x C), retrieved = query @ h8(M),
//   h8(x) = 1 - (1 - a*x)^256 = 256*a*x - O((a*x)^2), a*x <= ~7e-7.
// ||A||_F^2 = trace(M), computed in reduce4 from the bf16 partial sums.
//
// Pipeline (4 dispatches):
//   1. prep   : At = A^T bf16 + qb = bf16(query) + wsf[4]=0
//               ROUND 9: float4 transpose reads (16B/lane, was 16 scalar
//               dwords/thread -- G13 violation) + balanced grid (4096 cvt
//               blocks @24KB each = transpose blocks' load; was 1024 @48KB
//               -> cvt tail set prep's wall).
//   2. gemm_m3: P[z] = bf16(At @ At^T over K-chunk z), split-K=4, 256^2 tile,
//               4-phase schedule, XCD-chunked. FROZEN (round-8 control).
//   3. reduce4: Mb = bf16(sum_z P[z]) + trace -> wsf[4]. Grid 2048 (1 iter/
//               thread).
//   4. gemm_qm: out = c1 * (qb @ Mb^T), single-barrier 4-phase, FROZEN
//               (round-8: 79.5 us / MfmaUtil 36.4 / FETCH 49 MB / 0 confl).
//
// 4-phase K-tile schedule (both gemms; phase q = C-quadrant q, 16 MFMA):
//   q0: rd A-quad0 + B all (regs for whole tile); stA(t+1,h0)
//   q1: rd A-quad1;                               stA(t+1,h1)
//   q2: rd A-quad2;                               stB(t+2,h0)
//   q3: rd A-quad3; stB(t+2,h1); vmcnt(4)
// (gemm_m3: barrier/lgkm0 around MFMA per phase -- round-1 form.
//  gemm_qm: single-barrier form -- ledger in kernel comment.)
// Shared invariants:
//  - vmcnt(4)@q3 drains A(t+1), keeps B(t+2)'s 4 loads in flight; tail 0.
//  - stB@q2 overwrites Bs[buf] only after breg reg-capture drained @q0.
//  - stA@q0 overwrites As[buf^1], last read drained in t-1's final phase.
//  - LDS swizzle both-sides: physical 16B slot p of row r holds logical
//    k-slot p^(r&7); staging pre-swizzles the GLOBAL source column (linear
//    LDS dest, as global_load_lds requires), reads apply the same XOR.
// ============================================================================

#define K_DIM 4096
#define C_DIM 2048
#define B_DIM 8192
#define SPLITK 4
#define KCHUNK (K_DIM / SPLITK)

typedef __bf16 bf16x8 __attribute__((ext_vector_type(8)));
typedef float f32x4 __attribute__((ext_vector_type(4)));

#define VMCNT(n) asm volatile("s_waitcnt vmcnt(" #n ")" ::: "memory")
#define LGKMCNT0 asm volatile("s_waitcnt lgkmcnt(0)" ::: "memory")
#define SBAR __builtin_amdgcn_s_barrier()

__device__ __forceinline__ void async_load16(const void* g, void* l) {
  __builtin_amdgcn_global_load_lds(
      (const __attribute__((address_space(1))) void*)g,
      (__attribute__((address_space(3))) void*)l, 16, 0, 0);
}

// --------------------------- prep: transpose + cvt + wsf zero -------------
// Transpose blocks (b < 2048): 64x64 tile of A (K,C) fp32 -> At (C,K) bf16.
//   Phase 1: thread t reads float4 A[k0+kk+16p][c0 + 4*(t&15)] (16B/lane,
//   256B per 16-lane group, 4 passes) and scatters 4 bf16 into Ts[c][k]
//   (pitch 68 kills power-of-2 bank stride).
//   Phase 2: thread t reads 16 k-consecutive bf16 of row c = t>>2 and
//   writes 2x uint4 to At -- unchanged from round 8.
// Cvt blocks (b >= 2048, 4096 of them): qb = bf16(query), 4 iters/thread,
//   24 KB/block == transpose blocks' traffic (balanced tail).
__global__ __launch_bounds__(256) void prep_kernel(
    const float* __restrict__ A, __hip_bfloat16* __restrict__ At,
    const float* __restrict__ q, __hip_bfloat16* __restrict__ qb,
    float* __restrict__ wsf) {
  const int b = blockIdx.x;
  const int t = threadIdx.x;
  if (b < 2048) {  // ---- transpose tile
    __shared__ __align__(16) __hip_bfloat16 Ts[64 * 68];
    const int c0 = (b & 31) * 64;
    const int k0 = (b >> 5) * 64;
    const int kk = t >> 4;        // 16 rows per pass
    const int c4 = (t & 15) * 4;  // 4 consecutive cols per thread
#pragma unroll
    for (int p = 0; p < 4; ++p) {
      const int k = kk + p * 16;
      const float4 v = *(const float4*)&A[(size_t)(k0 + k) * C_DIM + c0 + c4];
      Ts[(c4 + 0) * 68 + k] = __float2bfloat16(v.x);
      Ts[(c4 + 1) * 68 + k] = __float2bfloat16(v.y);
      Ts[(c4 + 2) * 68 + k] = __float2bfloat16(v.z);
      Ts[(c4 + 3) * 68 + k] = __float2bfloat16(v.w);
    }
    __syncthreads();
    const int c = t >> 2;
    const int seg = t & 3;
    const __hip_bfloat16* src = Ts + c * 68 + seg * 16;
    union { uint2 d[2]; uint4 qv; } o0, o1;
    o0.d[0] = *(const uint2*)(src + 0);
    o0.d[1] = *(const uint2*)(src + 4);
    o1.d[0] = *(const uint2*)(src + 8);
    o1.d[1] = *(const uint2*)(src + 12);
    __hip_bfloat16* dst = At + (size_t)(c0 + c) * K_DIM + k0 + seg * 16;
    *(uint4*)(dst + 0) = o0.qv;
    *(uint4*)(dst + 8) = o1.qv;
  } else {  // ---- cvt query -> qb (4096 blocks, 4 iters/thread)
    if (b == 2048 && t == 0) wsf[4] = 0.0f;
    const int n4 = B_DIM * C_DIM / 4;
    int tid = (b - 2048) * 256 + t;
    for (int i = tid; i < n4; i += 4096 * 256) {
      float4 v = ((const float4*)q)[i];
      __hip_bfloat16 o[4] = {__float2bfloat16(v.x), __float2bfloat16(v.y),
                             __float2bfloat16(v.z), __float2bfloat16(v.w)};
      *(uint2*)(qb + 4 * (size_t)i) = *(const uint2*)o;
    }
  }
}

// --------------------- gemm_m3: P[z] = bf16(At @ At^T), K-chunk z ---------
// FROZEN (round-8 control). 256x256 tile, 8 waves (2Mx4N), wave tile 128x64,
// BK=64, double-buffered 128 KiB LDS, 4-phase 2-barrier schedule.
// Grid 256 = 8x8 tiles x 4 z, XCD-chunked: sw=(bid&7)*32+(bid>>3) bijective;
// XCD i owns one half z-slice -> union At fetch per XCD = 4 MiB = one L2.
__global__ __launch_bounds__(512, 2) void gemm_m3(
    const __hip_bfloat16* __restrict__ At, __hip_bfloat16* __restrict__ P) {
  constexpr int BK = 64;
  constexpr int NT = KCHUNK / BK;  // 16
  __shared__ __align__(16) __hip_bfloat16 As[2][256 * BK];
  __shared__ __align__(16) __hip_bfloat16 Bs[2][256 * BK];
  const int bid = blockIdx.x;
  const int sw = (bid & 7) * 32 + (bid >> 3);
  const int z = sw >> 6;           // [0,4)
  const int rem = sw & 63;
  const int tm_i = rem >> 3;       // [0,8)
  const int tn_i = rem & 7;        // [0,8)
  const int tid = threadIdx.x;
  const int wave = tid >> 6, lane = tid & 63;
  const int tile_m = tm_i * 256, tile_n = tn_i * 256;
  const int kstart = z * KCHUNK;
  const int wm = (wave >> 2) * 128, wn = (wave & 3) * 64;
  const int lr = lane >> 3, lcl = (lane & 7) ^ lr;
  const __hip_bfloat16* aBase =
      At + (size_t)(tile_m + wave * 16 + lr) * K_DIM + kstart + lcl * 8;
  const __hip_bfloat16* bBase =
      At + (size_t)(tile_n + wave * 16 + lr) * K_DIM + kstart + lcl * 8;
  const int l15 = lane & 15, lg = lane >> 4, l7 = lane & 7;

  auto stA = [&](int buf, int h, int t) {
    const __hip_bfloat16* s = aBase + (size_t)(h * 128) * K_DIM + (size_t)t * BK;
    __hip_bfloat16* d = &As[buf][(h * 128 + wave * 16) * BK];
    async_load16(s, d);
    async_load16(s + (size_t)8 * K_DIM, d + 8 * BK);
  };
  auto stB = [&](int buf, int h, int t) {
    const __hip_bfloat16* s = bBase + (size_t)(h * 128) * K_DIM + (size_t)t * BK;
    __hip_bfloat16* d = &Bs[buf][(h * 128 + wave * 16) * BK];
    async_load16(s, d);
    async_load16(s + (size_t)8 * K_DIM, d + 8 * BK);
  };

  f32x4 acc[8][4] = {};

  // prologue: A(0), B(0) must land; B(1)'s 4 loads stay in flight
  stA(0, 0, 0); stA(0, 1, 0);
  stB(0, 0, 0); stB(0, 1, 0);
  stB(1, 0, 1); stB(1, 1, 1);
  VMCNT(4);
  SBAR;

  for (int t = 0; t < NT; ++t) {
    const int buf = t & 1;
    bf16x8 breg[4][2];
#pragma unroll
    for (int q = 0; q < 4; ++q) {
      bf16x8 af[2][2];
#pragma unroll
      for (int f = 0; f < 2; ++f)
#pragma unroll
        for (int s = 0; s < 2; ++s)
          af[f][s] = *(const bf16x8*)&As[buf][(wm + q * 32 + f * 16 + l15) * BK +
                                             ((((s << 2) | lg) ^ l7) << 3)];
      if (q == 0) {
#pragma unroll
        for (int j = 0; j < 4; ++j)
#pragma unroll
          for (int s = 0; s < 2; ++s)
            breg[j][s] = *(const bf16x8*)&Bs[buf][(wn + j * 16 + l15) * BK +
                                                 ((((s << 2) | lg) ^ l7) << 3)];
      }
      if (q == 0 && t + 1 < NT) stA(buf ^ 1, 0, t + 1);
      if (q == 1 && t + 1 < NT) stA(buf ^ 1, 1, t + 1);
      if (q == 2 && t + 2 < NT) stB(buf, 0, t + 2);
      if (q == 3) {
        if (t + 2 < NT) {
          stB(buf, 1, t + 2);
          VMCNT(4);
        } else {
          VMCNT(0);
        }
      }
      SBAR;
      LGKMCNT0;
      __builtin_amdgcn_s_setprio(1);
#pragma unroll
      for (int s = 0; s < 2; ++s)
#pragma unroll
        for (int f = 0; f < 2; ++f)
#pragma unroll
          for (int j = 0; j < 4; ++j)
            acc[q * 2 + f][j] = __builtin_amdgcn_mfma_f32_16x16x32_bf16(
                af[f][s], breg[j][s], acc[q * 2 + f][j], 0, 0, 0);
      __builtin_amdgcn_s_setprio(0);
      SBAR;
    }
  }

  // epilogue: bf16 partial. C/D (16x16): col = lane&15, row = (lane>>4)*4+reg
  __hip_bfloat16* Pz = P + (size_t)z * C_DIM * C_DIM;
#pragma unroll
  for (int m = 0; m < 8; ++m) {
    const int gm = tile_m + wm + m * 16 + lg * 4;
#pragma unroll
    for (int j = 0; j < 4; ++j) {
      const int gn = tile_n + wn + j * 16 + l15;
#pragma unroll
      for (int r = 0; r < 4; ++r)
        Pz[(size_t)(gm + r) * C_DIM + gn] = __float2bfloat16(acc[m][j][r]);
    }
  }
}

// ------------------- reduce4: Mb = bf16(sum P[z]) + trace -----------------
// bf16 partial streams (4 x 8 MiB read + 8 MiB write). Grid 2048 -> exactly
// one 8-element group per thread.
__global__ __launch_bounds__(256) void reduce4_kernel(
    const __hip_bfloat16* __restrict__ P, __hip_bfloat16* __restrict__ Mb,
    float* __restrict__ wsf) {
  const size_t CC = (size_t)C_DIM * C_DIM;
  const int n8 = (int)(CC / 8);
  int tid = blockIdx.x * blockDim.x + threadIdx.x;
  int stride = gridDim.x * blockDim.x;
  float tsum = 0.0f;
  bool hit = false;
  for (int i = tid; i < n8; i += stride) {
    float acc[8] = {};
#pragma unroll
    for (int z = 0; z < SPLITK; ++z) {
      uint4 raw = *(const uint4*)(P + z * CC + (size_t)i * 8);
      const __hip_bfloat16* h = (const __hip_bfloat16*)&raw;
#pragma unroll
      for (int j = 0; j < 8; ++j) acc[j] += __bfloat162float(h[j]);
    }
    __hip_bfloat16 o[8];
#pragma unroll
    for (int j = 0; j < 8; ++j) o[j] = __float2bfloat16(acc[j]);
    *(uint4*)(Mb + (size_t)i * 8) = *(const uint4*)o;
    // diag of row g sits at flat index g*(C_DIM+1); the 8-elem window
    // [8i, 8i+8) contains at most one (spacing 2049 > 8).
    const int e0 = 8 * i;
    const int g = e0 >> 11;
    const int d = g * (C_DIM + 1);
    if (d >= e0 && d < e0 + 8) {
      tsum += acc[d - e0];
      hit = true;
    }
  }
  if (hit) atomicAdd(wsf + 4, tsum);
}

// --------------------------- gemm_qm: out = c1 * qb @ Mb^T ----------------
// FROZEN (round-8: 79.5 us, MfmaUtil 36.4, conflicts 0, FETCH 49 MB).
// Single-barrier 4-phase schedule. 256x256 tile, 8 waves (2Mx4N), wave tile
// 128x64, BK=64, double-buffered 128 KiB LDS. Grid 256, XCD-chunked.
// Ledger: stA@p0-post overwrites As[buf^1] (last reads drained lgkm0@
// p3-post(t-1), ordered by bar(p0,t)); stB@p3-post overwrites Bs[buf]
// (bfr reads drained lgkm0@p0/p2-post, ordered by bar(p3,t)); vmcnt(0)@
// region(p3) drains A(t+1)/B(t+1) (issued >=2 phases earlier, cheap);
// stB(t+2) issued after the vmcnt stays in flight 4 phases.
__global__ __launch_bounds__(512, 2) void gemm_qm(
    const __hip_bfloat16* __restrict__ Ab, const __hip_bfloat16* __restrict__ Bb,
    float* __restrict__ Fp, const float* __restrict__ ls,
    const float* __restrict__ wsf) {
  constexpr int BK = 64;
  constexpr int NT = C_DIM / BK;  // 32
  __shared__ __align__(16) __hip_bfloat16 As[2][256 * BK];
  __shared__ __align__(16) __hip_bfloat16 Bs[2][256 * BK];
  const int bid = blockIdx.x;
  const int sw = (bid & 7) * 32 + (bid >> 3);
  const int tn_i = sw & 7;    // [0,8)
  const int tm_i = sw >> 3;   // [0,32)
  const int tid = threadIdx.x;
  const int wave = tid >> 6, lane = tid & 63;
  const int tile_m = tm_i * 256, tile_n = tn_i * 256;
  const int wm = (wave >> 2) * 128, wn = (wave & 3) * 64;
  const int lr = lane >> 3, lcl = (lane & 7) ^ lr;
  const __hip_bfloat16* aBase =
      Ab + (size_t)(tile_m + wave * 16 + lr) * C_DIM + lcl * 8;
  const __hip_bfloat16* bBase =
      Bb + (size_t)(tile_n + wave * 16 + lr) * C_DIM + lcl * 8;
  const int l15 = lane & 15, lg = lane >> 4, l7 = lane & 7;

  auto stA = [&](int buf, int h, int t) {
    const __hip_bfloat16* s = aBase + (size_t)(h * 128) * C_DIM + (size_t)t * BK;
    __hip_bfloat16* d = &As[buf][(h * 128 + wave * 16) * BK];
    async_load16(s, d);
    async_load16(s + (size_t)8 * C_DIM, d + 8 * BK);
  };
  auto stB = [&](int buf, int h, int t) {
    const __hip_bfloat16* s = bBase + (size_t)(h * 128) * C_DIM + (size_t)t * BK;
    __hip_bfloat16* d = &Bs[buf][(h * 128 + wave * 16) * BK];
    async_load16(s, d);
    async_load16(s + (size_t)8 * C_DIM, d + 8 * BK);
  };

  f32x4 acc[8][4] = {};
  bf16x8 af[4], bfr[4];

  auto rdA = [&](int buf, int mh, int s) {
#pragma unroll
    for (int f = 0; f < 4; ++f)
      af[f] = *(const bf16x8*)&As[buf][(wm + mh * 64 + f * 16 + l15) * BK +
                                       (((s * 4 + lg) ^ l7) * 8)];
  };
  auto rdB = [&](int buf, int s) {
#pragma unroll
    for (int j = 0; j < 4; ++j)
      bfr[j] = *(const bf16x8*)&Bs[buf][(wn + j * 16 + l15) * BK +
                                        (((s * 4 + lg) ^ l7) * 8)];
  };
  auto mm = [&](int mh) {
    __builtin_amdgcn_s_setprio(1);
#pragma unroll
    for (int f = 0; f < 4; ++f)
#pragma unroll
      for (int j = 0; j < 4; ++j)
        acc[mh * 4 + f][j] = __builtin_amdgcn_mfma_f32_16x16x32_bf16(
            af[f], bfr[j], acc[mh * 4 + f][j], 0, 0, 0);
    __builtin_amdgcn_s_setprio(0);
  };

  // prologue: A(0),B(0) drained; B(1)'s 4 loads stay in flight
  stA(0, 0, 0); stA(0, 1, 0);
  stB(0, 0, 0); stB(0, 1, 0);
  stB(1, 0, 1); stB(1, 1, 1);
  VMCNT(4);
  SBAR;

  for (int t = 0; t < NT; ++t) {
    const int buf = t & 1;
    // ---- p0: (s0, mh0)
    rdA(buf, 0, 0);
    rdB(buf, 0);
    SBAR;
    if (t + 1 < NT) stA(buf ^ 1, 0, t + 1);
    LGKMCNT0;
    mm(0);
    // ---- p1: (s0, mh1)
    rdA(buf, 1, 0);
    SBAR;
    if (t + 1 < NT) stA(buf ^ 1, 1, t + 1);
    LGKMCNT0;
    mm(1);
    // ---- p2: (s1, mh0)
    rdA(buf, 0, 1);
    rdB(buf, 1);
    SBAR;
    LGKMCNT0;
    mm(0);
    // ---- p3: (s1, mh1)
    rdA(buf, 1, 1);
    VMCNT(0);  // drains A(t+1),B(t+1) (issued >=2 phases ago); cheap
    SBAR;
    if (t + 2 < NT) { stB(buf, 0, t + 2); stB(buf, 1, t + 2); }
    LGKMCNT0;
    mm(1);
  }

  // epilogue: C/D (16x16): col = lane&15, row = (lane>>4)*4 + reg
  const float c1 = 256.0f * fminf(expf(ls[0]), 5e-4f) / (wsf[4] + 1e-8f);
#pragma unroll
  for (int m = 0; m < 8; ++m) {
    const int gm = tile_m + wm + m * 16 + lg * 4;
#pragma unroll
    for (int j = 0; j < 4; ++j) {
      const int gn = tile_n + wn + j * 16 + l15;
#pragma unroll
      for (int r = 0; r < 4; ++r)
        Fp[(size_t)(gm + r) * C_DIM + gn] = c1 * acc[m][j][r];
    }
  }
}

// ------------------------------------------------------------- launch -----
extern "C" void kernel_launch(void* const* d_in, const int* in_sizes, int n_in,
                              void* d_out, int out_size, void* d_ws, size_t ws_size,
                              hipStream_t stream) {
  const float* query = (const float*)d_in[0];
  const float* A = (const float*)d_in[1];
  const float* ls = (const float*)d_in[2];
  float* out = (float*)d_out;

  char* ws = (char*)d_ws;
  float* wsf = (float*)ws;
  size_t off = 256;
  __hip_bfloat16* At = (__hip_bfloat16*)(ws + off);
  off += (size_t)C_DIM * K_DIM * 2;  // 16 MiB
  __hip_bfloat16* qb = (__hip_bfloat16*)(ws + off);
  off += (size_t)B_DIM * C_DIM * 2;  // 32 MiB
  __hip_bfloat16* Mb = (__hip_bfloat16*)(ws + off);  // 8 MiB

  // split-K bf16 partials live in the OUT buffer (4 x 8 MiB = 32 MiB of the
  // 64 MiB out); gemm_qm overwrites out afterwards (stream-ordered).
  __hip_bfloat16* P = (__hip_bfloat16*)out;

  // 1) At = A^T bf16 ; qb = bf16(query) ; wsf[4] = 0  (2048 + 4096 blocks)
  prep_kernel<<<6144, 256, 0, stream>>>(A, At, query, qb, wsf);
  // 2) P[z] = bf16(At @ At^T) over K-chunk z  (256 blocks, XCD-chunked)
  gemm_m3<<<256, 512, 0, stream>>>(At, P);
  // 3) Mb = bf16(sum_z P[z]) + trace -> wsf[4]
  reduce4_kernel<<<2048, 256, 0, stream>>>(P, Mb, wsf);
  // 4) out = c1 * qb @ Mb^T  (256 blocks, XCD-chunked)
  gemm_qm<<<256, 512, 0, stream>>>(qb, Mb, out, ls, wsf);
}

// Round 16
// 267.594 us; speedup vs baseline: 1.0343x; 1.0328x over previous
//
#include <hip/hip_runtime.h>
#include <hip/hip_bf16.h>
#include <cstdint>
#include <cstddef>

// ============================================================================
// CA3RecurrentMatrix: retrieved = query @ pinv8(A) @ A
//
// Math: with M = A^T A (C x C), retrieved = query @ h8(M),
//   h8(x) = 1 - (1 - a*x)^256 = 256*a*x - O((a*x)^2), a*x <= ~7e-7.
// ||A||_F^2 = trace(M), computed in reduce4 from the bf16 partial sums.
//
// Pipeline (4 dispatches):
//   1. prep   : At = A^T bf16 + qb = bf16(query) + wsf[4]=0  (round-9 form)
//   2. gemm_m3: P[z] = bf16(At @ At^T over K-chunk z), split-K=4, 256^2 tile,
//               4-phase schedule, XCD-chunked. FROZEN control.
//   3. reduce4: Mb = bf16(sum_z P[z]) + trace -> wsf[4]. FROZEN control.
//   4. gemm_qm: out = c1 * (qb @ Mb^T). ROUND 13: faithful m201 8-phase
//               schedule -- 2 K-tiles/iter, 1 half-tile staged per phase,
//               vmcnt(6) at phases 0/4 ONLY (3 half-tiles always in flight,
//               never drains to 0 mid-loop). Previous 7 variants all pinned
//               at ~35% MfmaUtil; all of them either drained vmcnt(0) per
//               tile or kept prefetch depth <=2 -- m218's isolated result
//               (counted-vmcnt inside 8-phase = +38-73%) was never applied
//               faithfully.
//
// gemm_qm 8-phase schedule (iter k computes tiles t0=2k (buf0), t1=2k+1
// (buf1); phase = [region: ds_reads + 1 stage (+vmcnt at p0/p4) | bar |
// lgkm0 | setprio(1) 16 MFMA setprio(0) | bar]):
//   p0: rdA(buf0,quad0)+rdB(buf0, all 8 b128); stA0(2k+1)->buf1; VMCNT(6)
//   p1: rdA(buf0,quad1);                       stA1(2k+1)->buf1
//   p2: rdA(buf0,quad2);                       stB0(2k+2)->buf0
//   p3: rdA(buf0,quad3);                       stB1(2k+2)->buf0
//   p4: rdA(buf1,quad0)+rdB(buf1);             stA0(2k+2)->buf0; VMCNT(6)*
//   p5: rdA(buf1,quad1);                       stA1(2k+2)->buf0
//   p6: rdA(buf1,quad2);                       stB0(2k+3)->buf1
//   p7: rdA(buf1,quad3);                       stB1(2k+3)->buf1
//   (* last iter: VMCNT(0) -- stages p2-p4 skipped leave <6 outstanding, so
//      vmcnt(6) would not wait for the A(31) loads issued at p0/p1.)
// Hazard ledger (per-stage, re-derived):
//  - stA->buf1 @p0/p1: buf1 A last read at p7(k-1) regions, drained by
//    lgkm0(p7) before bar2(p7) -> all waves past bar2(p7) before p0 region.
//  - stB->buf0 @p2/p3: buf0 B reg-captured at p0 region, drained lgkm0(p0)
//    before bar2(p0); stage is after bar2(p1). B-stage touches Bs only. OK.
//  - stA->buf0 @p4/p5: buf0 A last read at p3 region, drained lgkm0(p3)
//    before bar2(p3); stage after bar2(p3).
//  - stB->buf1 @p6/p7: buf1 B captured at p4 region, drained lgkm0(p4)
//    before bar2(p4); stage after bar2(p5).
//  - VMCNT(6)@p0: leaves {p6,p7 stages of k-1, p0 stage} = 6 newest; all
//    older (incl. A(2k)@p4/p5(k-1), B(2k)@p2/p3(k-1)) drained -> tile 2k
//    readable. VMCNT(6)@p4: leaves {p2,p3,p4} -> drains A(2k+1)@p0/p1 and
//    B(2k+1)@p6/p7(k-1) -> tile 2k+1 readable. Steady-state outstanding
//    never exceeds 14, never drains below 6 (except final iter).
//  - Prologue: stage A(0),B(0)->buf0, B(1)->buf1; VMCNT(4) (B(1) in
//    flight); bar. Iter-0 p0/p4 ledger identical to steady state.
//  - LDS swizzle both-sides: physical 16B slot p of row r holds logical
//    k-slot p^(r&7); staging pre-swizzles the GLOBAL source column (linear
//    LDS dest per global_load_lds), reads apply the same XOR. (0 bank
//    conflicts measured.)  XCD-chunked grid (FETCH 135->49 MB measured).
// ============================================================================

#define K_DIM 4096
#define C_DIM 2048
#define B_DIM 8192
#define SPLITK 4
#define KCHUNK (K_DIM / SPLITK)

typedef __bf16 bf16x8 __attribute__((ext_vector_type(8)));
typedef float f32x4 __attribute__((ext_vector_type(4)));

#define VMCNT(n) asm volatile("s_waitcnt vmcnt(" #n ")" ::: "memory")
#define LGKMCNT0 asm volatile("s_waitcnt lgkmcnt(0)" ::: "memory")
#define SBAR __builtin_amdgcn_s_barrier()

__device__ __forceinline__ void async_load16(const void* g, void* l) {
  __builtin_amdgcn_global_load_lds(
      (const __attribute__((address_space(1))) void*)g,
      (__attribute__((address_space(3))) void*)l, 16, 0, 0);
}

// --------------------------- prep: transpose + cvt + wsf zero -------------
__global__ __launch_bounds__(256) void prep_kernel(
    const float* __restrict__ A, __hip_bfloat16* __restrict__ At,
    const float* __restrict__ q, __hip_bfloat16* __restrict__ qb,
    float* __restrict__ wsf) {
  const int b = blockIdx.x;
  const int t = threadIdx.x;
  if (b < 2048) {  // ---- transpose tile
    __shared__ __align__(16) __hip_bfloat16 Ts[64 * 68];
    const int c0 = (b & 31) * 64;
    const int k0 = (b >> 5) * 64;
    const int kk = t >> 4;
    const int c4 = (t & 15) * 4;
#pragma unroll
    for (int p = 0; p < 4; ++p) {
      const int k = kk + p * 16;
      const float4 v = *(const float4*)&A[(size_t)(k0 + k) * C_DIM + c0 + c4];
      Ts[(c4 + 0) * 68 + k] = __float2bfloat16(v.x);
      Ts[(c4 + 1) * 68 + k] = __float2bfloat16(v.y);
      Ts[(c4 + 2) * 68 + k] = __float2bfloat16(v.z);
      Ts[(c4 + 3) * 68 + k] = __float2bfloat16(v.w);
    }
    __syncthreads();
    const int c = t >> 2;
    const int seg = t & 3;
    const __hip_bfloat16* src = Ts + c * 68 + seg * 16;
    union { uint2 d[2]; uint4 qv; } o0, o1;
    o0.d[0] = *(const uint2*)(src + 0);
    o0.d[1] = *(const uint2*)(src + 4);
    o1.d[0] = *(const uint2*)(src + 8);
    o1.d[1] = *(const uint2*)(src + 12);
    __hip_bfloat16* dst = At + (size_t)(c0 + c) * K_DIM + k0 + seg * 16;
    *(uint4*)(dst + 0) = o0.qv;
    *(uint4*)(dst + 8) = o1.qv;
  } else {  // ---- cvt query -> qb
    if (b == 2048 && t == 0) wsf[4] = 0.0f;
    const int n4 = B_DIM * C_DIM / 4;
    int tid = (b - 2048) * 256 + t;
    for (int i = tid; i < n4; i += 4096 * 256) {
      float4 v = ((const float4*)q)[i];
      __hip_bfloat16 o[4] = {__float2bfloat16(v.x), __float2bfloat16(v.y),
                             __float2bfloat16(v.z), __float2bfloat16(v.w)};
      *(uint2*)(qb + 4 * (size_t)i) = *(const uint2*)o;
    }
  }
}

// --------------------- gemm_m3: P[z] = bf16(At @ At^T), K-chunk z ---------
// FROZEN control (round-8 form).
__global__ __launch_bounds__(512, 2) void gemm_m3(
    const __hip_bfloat16* __restrict__ At, __hip_bfloat16* __restrict__ P) {
  constexpr int BK = 64;
  constexpr int NT = KCHUNK / BK;  // 16
  __shared__ __align__(16) __hip_bfloat16 As[2][256 * BK];
  __shared__ __align__(16) __hip_bfloat16 Bs[2][256 * BK];
  const int bid = blockIdx.x;
  const int sw = (bid & 7) * 32 + (bid >> 3);
  const int z = sw >> 6;
  const int rem = sw & 63;
  const int tm_i = rem >> 3;
  const int tn_i = rem & 7;
  const int tid = threadIdx.x;
  const int wave = tid >> 6, lane = tid & 63;
  const int tile_m = tm_i * 256, tile_n = tn_i * 256;
  const int kstart = z * KCHUNK;
  const int wm = (wave >> 2) * 128, wn = (wave & 3) * 64;
  const int lr = lane >> 3, lcl = (lane & 7) ^ lr;
  const __hip_bfloat16* aBase =
      At + (size_t)(tile_m + wave * 16 + lr) * K_DIM + kstart + lcl * 8;
  const __hip_bfloat16* bBase =
      At + (size_t)(tile_n + wave * 16 + lr) * K_DIM + kstart + lcl * 8;
  const int l15 = lane & 15, lg = lane >> 4, l7 = lane & 7;

  auto stA = [&](int buf, int h, int t) {
    const __hip_bfloat16* s = aBase + (size_t)(h * 128) * K_DIM + (size_t)t * BK;
    __hip_bfloat16* d = &As[buf][(h * 128 + wave * 16) * BK];
    async_load16(s, d);
    async_load16(s + (size_t)8 * K_DIM, d + 8 * BK);
  };
  auto stB = [&](int buf, int h, int t) {
    const __hip_bfloat16* s = bBase + (size_t)(h * 128) * K_DIM + (size_t)t * BK;
    __hip_bfloat16* d = &Bs[buf][(h * 128 + wave * 16) * BK];
    async_load16(s, d);
    async_load16(s + (size_t)8 * K_DIM, d + 8 * BK);
  };

  f32x4 acc[8][4] = {};

  stA(0, 0, 0); stA(0, 1, 0);
  stB(0, 0, 0); stB(0, 1, 0);
  stB(1, 0, 1); stB(1, 1, 1);
  VMCNT(4);
  SBAR;

  for (int t = 0; t < NT; ++t) {
    const int buf = t & 1;
    bf16x8 breg[4][2];
#pragma unroll
    for (int q = 0; q < 4; ++q) {
      bf16x8 af[2][2];
#pragma unroll
      for (int f = 0; f < 2; ++f)
#pragma unroll
        for (int s = 0; s < 2; ++s)
          af[f][s] = *(const bf16x8*)&As[buf][(wm + q * 32 + f * 16 + l15) * BK +
                                             ((((s << 2) | lg) ^ l7) << 3)];
      if (q == 0) {
#pragma unroll
        for (int j = 0; j < 4; ++j)
#pragma unroll
          for (int s = 0; s < 2; ++s)
            breg[j][s] = *(const bf16x8*)&Bs[buf][(wn + j * 16 + l15) * BK +
                                                 ((((s << 2) | lg) ^ l7) << 3)];
      }
      if (q == 0 && t + 1 < NT) stA(buf ^ 1, 0, t + 1);
      if (q == 1 && t + 1 < NT) stA(buf ^ 1, 1, t + 1);
      if (q == 2 && t + 2 < NT) stB(buf, 0, t + 2);
      if (q == 3) {
        if (t + 2 < NT) {
          stB(buf, 1, t + 2);
          VMCNT(4);
        } else {
          VMCNT(0);
        }
      }
      SBAR;
      LGKMCNT0;
      __builtin_amdgcn_s_setprio(1);
#pragma unroll
      for (int s = 0; s < 2; ++s)
#pragma unroll
        for (int f = 0; f < 2; ++f)
#pragma unroll
          for (int j = 0; j < 4; ++j)
            acc[q * 2 + f][j] = __builtin_amdgcn_mfma_f32_16x16x32_bf16(
                af[f][s], breg[j][s], acc[q * 2 + f][j], 0, 0, 0);
      __builtin_amdgcn_s_setprio(0);
      SBAR;
    }
  }

  __hip_bfloat16* Pz = P + (size_t)z * C_DIM * C_DIM;
#pragma unroll
  for (int m = 0; m < 8; ++m) {
    const int gm = tile_m + wm + m * 16 + lg * 4;
#pragma unroll
    for (int j = 0; j < 4; ++j) {
      const int gn = tile_n + wn + j * 16 + l15;
#pragma unroll
      for (int r = 0; r < 4; ++r)
        Pz[(size_t)(gm + r) * C_DIM + gn] = __float2bfloat16(acc[m][j][r]);
    }
  }
}

// ------------------- reduce4: Mb = bf16(sum P[z]) + trace -----------------
__global__ __launch_bounds__(256) void reduce4_kernel(
    const __hip_bfloat16* __restrict__ P, __hip_bfloat16* __restrict__ Mb,
    float* __restrict__ wsf) {
  const size_t CC = (size_t)C_DIM * C_DIM;
  const int n8 = (int)(CC / 8);
  int tid = blockIdx.x * blockDim.x + threadIdx.x;
  int stride = gridDim.x * blockDim.x;
  float tsum = 0.0f;
  bool hit = false;
  for (int i = tid; i < n8; i += stride) {
    float acc[8] = {};
#pragma unroll
    for (int z = 0; z < SPLITK; ++z) {
      uint4 raw = *(const uint4*)(P + z * CC + (size_t)i * 8);
      const __hip_bfloat16* h = (const __hip_bfloat16*)&raw;
#pragma unroll
      for (int j = 0; j < 8; ++j) acc[j] += __bfloat162float(h[j]);
    }
    __hip_bfloat16 o[8];
#pragma unroll
    for (int j = 0; j < 8; ++j) o[j] = __float2bfloat16(acc[j]);
    *(uint4*)(Mb + (size_t)i * 8) = *(const uint4*)o;
    const int e0 = 8 * i;
    const int g = e0 >> 11;
    const int d = g * (C_DIM + 1);
    if (d >= e0 && d < e0 + 8) {
      tsum += acc[d - e0];
      hit = true;
    }
  }
  if (hit) atomicAdd(wsf + 4, tsum);
}

// --------------------------- gemm_qm: out = c1 * qb @ Mb^T ----------------
// ROUND 13: faithful m201 8-phase (see header ledger). 256x256 tile, 8
// waves (2Mx4N), wave tile 128x64, BK=64, 2 K-tiles/iter, double-buffered
// 128 KiB LDS. Grid 256, XCD-chunked.
__global__ __launch_bounds__(512, 2) void gemm_qm(
    const __hip_bfloat16* __restrict__ Ab, const __hip_bfloat16* __restrict__ Bb,
    float* __restrict__ Fp, const float* __restrict__ ls,
    const float* __restrict__ wsf) {
  constexpr int BK = 64;
  constexpr int NT = C_DIM / BK;   // 32
  constexpr int NIT = NT / 2;      // 16
  __shared__ __align__(16) __hip_bfloat16 As[2][256 * BK];
  __shared__ __align__(16) __hip_bfloat16 Bs[2][256 * BK];
  const int bid = blockIdx.x;
  const int sw = (bid & 7) * 32 + (bid >> 3);
  const int tn_i = sw & 7;
  const int tm_i = sw >> 3;
  const int tid = threadIdx.x;
  const int wave = tid >> 6, lane = tid & 63;
  const int tile_m = tm_i * 256, tile_n = tn_i * 256;
  const int wm = (wave >> 2) * 128, wn = (wave & 3) * 64;
  const int lr = lane >> 3, lcl = (lane & 7) ^ lr;
  const __hip_bfloat16* aBase =
      Ab + (size_t)(tile_m + wave * 16 + lr) * C_DIM + lcl * 8;
  const __hip_bfloat16* bBase =
      Bb + (size_t)(tile_n + wave * 16 + lr) * C_DIM + lcl * 8;
  const int l15 = lane & 15, lg = lane >> 4, l7 = lane & 7;

  auto stA = [&](int buf, int h, int t) {
    const __hip_bfloat16* s = aBase + (size_t)(h * 128) * C_DIM + (size_t)t * BK;
    __hip_bfloat16* d = &As[buf][(h * 128 + wave * 16) * BK];
    async_load16(s, d);
    async_load16(s + (size_t)8 * C_DIM, d + 8 * BK);
  };
  auto stB = [&](int buf, int h, int t) {
    const __hip_bfloat16* s = bBase + (size_t)(h * 128) * C_DIM + (size_t)t * BK;
    __hip_bfloat16* d = &Bs[buf][(h * 128 + wave * 16) * BK];
    async_load16(s, d);
    async_load16(s + (size_t)8 * C_DIM, d + 8 * BK);
  };

  f32x4 acc[8][4] = {};
  bf16x8 breg[4][2], af[2][2];

  auto rdA = [&](int buf, int q) {
#pragma unroll
    for (int f = 0; f < 2; ++f)
#pragma unroll
      for (int s = 0; s < 2; ++s)
        af[f][s] = *(const bf16x8*)&As[buf][(wm + q * 32 + f * 16 + l15) * BK +
                                           ((((s << 2) | lg) ^ l7) << 3)];
  };
  auto rdB = [&](int buf) {
#pragma unroll
    for (int j = 0; j < 4; ++j)
#pragma unroll
      for (int s = 0; s < 2; ++s)
        breg[j][s] = *(const bf16x8*)&Bs[buf][(wn + j * 16 + l15) * BK +
                                             ((((s << 2) | lg) ^ l7) << 3)];
  };
  auto mm = [&](int q) {
    __builtin_amdgcn_s_setprio(1);
#pragma unroll
    for (int s = 0; s < 2; ++s)
#pragma unroll
      for (int f = 0; f < 2; ++f)
#pragma unroll
        for (int j = 0; j < 4; ++j)
          acc[q * 2 + f][j] = __builtin_amdgcn_mfma_f32_16x16x32_bf16(
              af[f][s], breg[j][s], acc[q * 2 + f][j], 0, 0, 0);
    __builtin_amdgcn_s_setprio(0);
  };

  // prologue: A(0),B(0)->buf0 land; B(1)->buf1 stays in flight (4 loads)
  stA(0, 0, 0); stA(0, 1, 0);
  stB(0, 0, 0); stB(0, 1, 0);
  stB(1, 0, 1); stB(1, 1, 1);
  VMCNT(4);
  SBAR;

  for (int k = 0; k < NIT; ++k) {
    const int t1 = 2 * k + 1;
    const bool st2 = (2 * k + 2 < NT);   // k < NIT-1
    const bool st3 = (2 * k + 3 < NT);   // k < NIT-1
    // ---- p0: quad0(t0,buf0) + B(t0) capture; stage A0(t1)->buf1; vmcnt(6)
    rdA(0, 0); rdB(0);
    stA(1, 0, t1);
    VMCNT(6);
    SBAR; LGKMCNT0; mm(0); SBAR;
    // ---- p1: quad1(t0); stage A1(t1)->buf1
    rdA(0, 1);
    stA(1, 1, t1);
    SBAR; LGKMCNT0; mm(1); SBAR;
    // ---- p2: quad2(t0); stage B0(t0+2)->buf0
    rdA(0, 2);
    if (st2) stB(0, 0, 2 * k + 2);
    SBAR; LGKMCNT0; mm(2); SBAR;
    // ---- p3: quad3(t0); stage B1(t0+2)->buf0
    rdA(0, 3);
    if (st2) stB(0, 1, 2 * k + 2);
    SBAR; LGKMCNT0; mm(3); SBAR;
    // ---- p4: quad0(t1,buf1) + B(t1) capture; stage A0(t0+2)->buf0
    rdA(1, 0); rdB(1);
    if (st2) {
      stA(0, 0, 2 * k + 2);
      VMCNT(6);
    } else {
      VMCNT(0);  // final iter: <6 outstanding, must drain A(t1) explicitly
    }
    SBAR; LGKMCNT0; mm(0); SBAR;
    // ---- p5: quad1(t1); stage A1(t0+2)->buf0
    rdA(1, 1);
    if (st2) stA(0, 1, 2 * k + 2);
    SBAR; LGKMCNT0; mm(1); SBAR;
    // ---- p6: quad2(t1); stage B0(t1+2)->buf1
    rdA(1, 2);
    if (st3) stB(1, 0, 2 * k + 3);
    SBAR; LGKMCNT0; mm(2); SBAR;
    // ---- p7: quad3(t1); stage B1(t1+2)->buf1
    rdA(1, 3);
    if (st3) stB(1, 1, 2 * k + 3);
    SBAR; LGKMCNT0; mm(3); SBAR;
  }

  // epilogue: C/D (16x16): col = lane&15, row = (lane>>4)*4 + reg
  const float c1 = 256.0f * fminf(expf(ls[0]), 5e-4f) / (wsf[4] + 1e-8f);
#pragma unroll
  for (int m = 0; m < 8; ++m) {
    const int gm = tile_m + wm + m * 16 + lg * 4;
#pragma unroll
    for (int j = 0; j < 4; ++j) {
      const int gn = tile_n + wn + j * 16 + l15;
#pragma unroll
      for (int r = 0; r < 4; ++r)
        Fp[(size_t)(gm + r) * C_DIM + gn] = c1 * acc[m][j][r];
    }
  }
}

// ------------------------------------------------------------- launch -----
extern "C" void kernel_launch(void* const* d_in, const int* in_sizes, int n_in,
                              void* d_out, int out_size, void* d_ws, size_t ws_size,
                              hipStream_t stream) {
  const float* query = (const float*)d_in[0];
  const float* A = (const float*)d_in[1];
  const float* ls = (const float*)d_in[2];
  float* out = (float*)d_out;

  char* ws = (char*)d_ws;
  float* wsf = (float*)ws;
  size_t off = 256;
  __hip_bfloat16* At = (__hip_bfloat16*)(ws + off);
  off += (size_t)C_DIM * K_DIM * 2;  // 16 MiB
  __hip_bfloat16* qb = (__hip_bfloat16*)(ws + off);
  off += (size_t)B_DIM * C_DIM * 2;  // 32 MiB
  __hip_bfloat16* Mb = (__hip_bfloat16*)(ws + off);  // 8 MiB

  // split-K bf16 partials live in the OUT buffer (4 x 8 MiB of 64 MiB out);
  // gemm_qm overwrites out afterwards (stream-ordered).
  __hip_bfloat16* P = (__hip_bfloat16*)out;

  // 1) At = A^T bf16 ; qb = bf16(query) ; wsf[4] = 0
  prep_kernel<<<6144, 256, 0, stream>>>(A, At, query, qb, wsf);
  // 2) P[z] = bf16(At @ At^T) over K-chunk z  (256 blocks, XCD-chunked)
  gemm_m3<<<256, 512, 0, stream>>>(At, P);
  // 3) Mb = bf16(sum_z P[z]) + trace -> wsf[4]
  reduce4_kernel<<<2048, 256, 0, stream>>>(P, Mb, wsf);
  // 4) out = c1 * qb @ Mb^T  (256 blocks, XCD-chunked, m201 8-phase)
  gemm_qm<<<256, 512, 0, stream>>>(qb, Mb, out, ls, wsf);
}